// Round 6
// baseline (242.654 us; speedup 1.0000x reference)
//
#include <hip/hip_runtime.h>
#include <hip/hip_bf16.h>

// Problem constants (from reference)
#define BATCH   16384
#define C_SEL   32
#define C_TOTAL 64
#define IN_F    128
#define OUT_F   128

#define BM      64    // batch rows per job
#define NGRP    32    // mtile groups (blocks per channel)
#define NJOBS   8     // jobs per block:  NGRP*NJOBS*BM == BATCH

typedef __bf16 bf16x8 __attribute__((ext_vector_type(8)));
typedef float  f32x4  __attribute__((ext_vector_type(4)));

__device__ __forceinline__ bf16x8 cvt_bf16x8(const float4 f0, const float4 f1) {
    bf16x8 a;
    a[0] = (__bf16)f0.x; a[1] = (__bf16)f0.y; a[2] = (__bf16)f0.z; a[3] = (__bf16)f0.w;
    a[4] = (__bf16)f1.x; a[5] = (__bf16)f1.y; a[6] = (__bf16)f1.z; a[7] = (__bf16)f1.w;
    return a;
}

__global__ __launch_bounds__(256, 4) void pl_mfma_kernel(
    const float* __restrict__ inp,       // (BATCH, C_SEL, IN_F)
    const float* __restrict__ weight,    // (C_TOTAL, OUT_F, IN_F)
    const float* __restrict__ bias,      // (C_TOTAL, OUT_F)
    const int*   __restrict__ channels,  // (C_SEL,)
    float*       __restrict__ out)       // (BATCH, C_SEL, OUT_F)
{
    // W[ch] as bf16 [128][128] = 32 KB exactly; bank-conflict-free via 16B-unit XOR swizzle.
    __shared__ __bf16 ldsW[OUT_F * IN_F];

    const int bid = blockIdx.x;          // 1024 blocks
    const int c   = bid & 31;            // channel fastest
    const int g   = bid >> 5;            // mtile group 0..31
    const int ch  = channels[c];

    const int t  = threadIdx.x;
    const int w  = t >> 6;               // wave 0..3 -> batch rows [w*16, w*16+16)
    const int l  = t & 63;
    const int lr = l & 15;               // In-fragment: batch row; W-fragment: out feature
    const int lg = l >> 4;               // k-group 0..3

    // per-lane A base (floats): job j adds j*JSTRIDE
    const size_t JSTRIDE = (size_t)NGRP * BM * C_SEL * IN_F;   // 8,388,608 floats
    const float* abase = inp + (size_t)g * BM * C_SEL * IN_F
                       + ((size_t)(w * 16 + lr) * C_SEL + (size_t)c) * IN_F + lg * 8;

    // ---- prologue: issue job 0 and job 1 A-loads (fire HBM early) ----
    float4 raA[8], raB[8];
    #pragma unroll
    for (int ks = 0; ks < 4; ++ks) {
        raA[2 * ks]     = *reinterpret_cast<const float4*>(abase + ks * 32);
        raA[2 * ks + 1] = *reinterpret_cast<const float4*>(abase + ks * 32 + 4);
    }
    #pragma unroll
    for (int ks = 0; ks < 4; ++ks) {
        raB[2 * ks]     = *reinterpret_cast<const float4*>(abase + JSTRIDE + ks * 32);
        raB[2 * ks + 1] = *reinterpret_cast<const float4*>(abase + JSTRIDE + ks * 32 + 4);
    }

    // ---- bias into persistent registers (once, no LDS) ----
    // lane needs bias[ch][nt*16 + lg*4 .. +3] (D rows it owns)
    f32x4 bv4[8];
    {
        const float* bsrc = bias + (size_t)ch * OUT_F + lg * 4;
        #pragma unroll
        for (int nt = 0; nt < 8; ++nt)
            bv4[nt] = *reinterpret_cast<const f32x4*>(bsrc + nt * 16);
    }

    // ---- stage W[ch] fp32 -> bf16 into LDS once (swizzled 16B units) ----
    const float* wsrc = weight + (size_t)ch * (OUT_F * IN_F);
    #pragma unroll
    for (int i = 0; i < 8; ++i) {
        const int fidx = i * 2048 + t * 8;
        const int row  = fidx >> 7;
        const int u    = (fidx & 127) >> 3;
        const float4 f0 = *reinterpret_cast<const float4*>(wsrc + fidx);
        const float4 f1 = *reinterpret_cast<const float4*>(wsrc + fidx + 4);
        const int up = u ^ (row & 7);
        *reinterpret_cast<bf16x8*>(&ldsW[row * IN_F + up * 8]) = cvt_bf16x8(f0, f1);
    }

    __syncthreads();

    // per-lane output base (floats): lane stores float4 at (row m = .. + lr, col o = nt*16 + lg*4)
    float* obase = out + (size_t)g * BM * C_SEL * OUT_F
                 + ((size_t)(w * 16 + lr) * C_SEL + (size_t)c) * OUT_F + lg * 4;

    // ---- job loop, manually 2x-unrolled so raA/raB indexing stays static ----
    #pragma unroll
    for (int jj = 0; jj < NJOBS; jj += 2) {
        // ===== even job jj (consumes raA) =====
        {
            // 1) convert landing buffer -> bf16 fragments (raA dies here)
            bf16x8 af[4];
            #pragma unroll
            for (int ks = 0; ks < 4; ++ks) af[ks] = cvt_bf16x8(raA[2 * ks], raA[2 * ks + 1]);

            // 2) immediately issue job jj+2's loads (max lead time before consumption)
            if (jj + 2 < NJOBS) {
                const float* p = abase + (size_t)(jj + 2) * JSTRIDE;
                #pragma unroll
                for (int ks = 0; ks < 4; ++ks) {
                    raA[2 * ks]     = *reinterpret_cast<const float4*>(p + ks * 32);
                    raA[2 * ks + 1] = *reinterpret_cast<const float4*>(p + ks * 32 + 4);
                }
            }

            // 3) acc init = bias (register copies, no memory dependency)
            f32x4 acc[8];
            #pragma unroll
            for (int nt = 0; nt < 8; ++nt) acc[nt] = bv4[nt];

            // 4) MFMA: D[o][m] = W * In^T (W = A-operand from LDS, In = B-operand)
            #pragma unroll
            for (int ks = 0; ks < 4; ++ks) {
                #pragma unroll
                for (int nt = 0; nt < 8; ++nt) {
                    const int row = nt * 16 + lr;                 // out feature (W row)
                    const int u   = (ks * 4 + lg) ^ (lr & 7);     // swizzled 16B unit
                    const bf16x8 w8 = *reinterpret_cast<const bf16x8*>(&ldsW[row * IN_F + u * 8]);
                    acc[nt] = __builtin_amdgcn_mfma_f32_16x16x32_bf16(w8, af[ks], acc[nt], 0, 0, 0);
                }
            }

            // 5) epilogue: 8 dwordx4 stores (bias already in acc)
            float* o = obase + (size_t)jj * JSTRIDE;
            #pragma unroll
            for (int nt = 0; nt < 8; ++nt) {
                *reinterpret_cast<float4*>(o + nt * 16) =
                    *reinterpret_cast<const float4*>(&acc[nt]);
            }
        }
        // ===== odd job jj+1 (consumes raB) =====
        {
            bf16x8 af[4];
            #pragma unroll
            for (int ks = 0; ks < 4; ++ks) af[ks] = cvt_bf16x8(raB[2 * ks], raB[2 * ks + 1]);

            if (jj + 3 < NJOBS) {
                const float* p = abase + (size_t)(jj + 3) * JSTRIDE;
                #pragma unroll
                for (int ks = 0; ks < 4; ++ks) {
                    raB[2 * ks]     = *reinterpret_cast<const float4*>(p + ks * 32);
                    raB[2 * ks + 1] = *reinterpret_cast<const float4*>(p + ks * 32 + 4);
                }
            }

            f32x4 acc[8];
            #pragma unroll
            for (int nt = 0; nt < 8; ++nt) acc[nt] = bv4[nt];

            #pragma unroll
            for (int ks = 0; ks < 4; ++ks) {
                #pragma unroll
                for (int nt = 0; nt < 8; ++nt) {
                    const int row = nt * 16 + lr;
                    const int u   = (ks * 4 + lg) ^ (lr & 7);
                    const bf16x8 w8 = *reinterpret_cast<const bf16x8*>(&ldsW[row * IN_F + u * 8]);
                    acc[nt] = __builtin_amdgcn_mfma_f32_16x16x32_bf16(w8, af[ks], acc[nt], 0, 0, 0);
                }
            }

            float* o = obase + (size_t)(jj + 1) * JSTRIDE;
            #pragma unroll
            for (int nt = 0; nt < 8; ++nt) {
                *reinterpret_cast<float4*>(o + nt * 16) =
                    *reinterpret_cast<const float4*>(&acc[nt]);
            }
        }
    }
}

extern "C" void kernel_launch(void* const* d_in, const int* in_sizes, int n_in,
                              void* d_out, int out_size, void* d_ws, size_t ws_size,
                              hipStream_t stream) {
    const float* inp      = (const float*)d_in[0];
    const float* weight   = (const float*)d_in[1];
    const float* bias     = (const float*)d_in[2];
    const int*   channels = (const int*)d_in[3];
    float*       out      = (float*)d_out;

    dim3 grid(C_SEL * NGRP);   // 1024 blocks, channel-fastest
    dim3 block(256);
    pl_mfma_kernel<<<grid, block, 0, stream>>>(inp, weight, bias, channels, out);
}

// Round 7
// 133.263 us; speedup vs baseline: 1.8209x; 1.8209x over previous
//
#include <hip/hip_runtime.h>
#include <hip/hip_bf16.h>

// Problem constants (from reference)
#define BATCH   16384
#define C_SEL   32
#define C_TOTAL 64
#define IN_F    128
#define OUT_F   128

#define BM      64    // batch rows per job
#define NGRP    32    // mtile groups (blocks per channel)
#define NJOBS   8     // jobs per block:  NGRP*NJOBS*BM == BATCH

typedef __bf16 bf16x8 __attribute__((ext_vector_type(8)));
typedef float  f32x4  __attribute__((ext_vector_type(4)));

__device__ __forceinline__ bf16x8 cvt_bf16x8(const float4 f0, const float4 f1) {
    bf16x8 a;
    a[0] = (__bf16)f0.x; a[1] = (__bf16)f0.y; a[2] = (__bf16)f0.z; a[3] = (__bf16)f0.w;
    a[4] = (__bf16)f1.x; a[5] = (__bf16)f1.y; a[6] = (__bf16)f1.z; a[7] = (__bf16)f1.w;
    return a;
}

__global__ __launch_bounds__(256, 4) void pl_mfma_kernel(
    const float* __restrict__ inp,       // (BATCH, C_SEL, IN_F)
    const float* __restrict__ weight,    // (C_TOTAL, OUT_F, IN_F)
    const float* __restrict__ bias,      // (C_TOTAL, OUT_F)
    const int*   __restrict__ channels,  // (C_SEL,)
    float*       __restrict__ out)       // (BATCH, C_SEL, OUT_F)
{
    // W[ch] as bf16 [128][128] = 32 KB; bank-conflict-free via 16B-unit XOR swizzle.
    __shared__ __bf16 ldsW[OUT_F * IN_F];
    __shared__ alignas(16) float ldsB[OUT_F];   // bias, 512 B

    const int bid = blockIdx.x;          // 1024 blocks
    const int c   = bid & 31;            // channel fastest
    const int g   = bid >> 5;            // mtile group 0..31
    const int ch  = channels[c];

    const int t  = threadIdx.x;
    const int w  = t >> 6;               // wave 0..3 -> batch rows [w*16, w*16+16)
    const int l  = t & 63;
    const int lr = l & 15;               // In-fragment: batch row; W-fragment: out feature
    const int lg = l >> 4;               // k-group 0..3

    // per-lane A base (floats): job j adds j*JSTRIDE
    const size_t JSTRIDE = (size_t)NGRP * BM * C_SEL * IN_F;   // 8,388,608 floats
    const float* abase = inp + (size_t)g * BM * C_SEL * IN_F
                       + ((size_t)(w * 16 + lr) * C_SEL + (size_t)c) * IN_F + lg * 8;

    // ---- prologue: issue job 0 and job 1 A-loads (fire HBM early) ----
    float4 raA[8], raB[8];
    #pragma unroll
    for (int ks = 0; ks < 4; ++ks) {
        raA[2 * ks]     = *reinterpret_cast<const float4*>(abase + ks * 32);
        raA[2 * ks + 1] = *reinterpret_cast<const float4*>(abase + ks * 32 + 4);
    }
    #pragma unroll
    for (int ks = 0; ks < 4; ++ks) {
        raB[2 * ks]     = *reinterpret_cast<const float4*>(abase + JSTRIDE + ks * 32);
        raB[2 * ks + 1] = *reinterpret_cast<const float4*>(abase + JSTRIDE + ks * 32 + 4);
    }

    // ---- stage W[ch] fp32 -> bf16 into LDS once (swizzled 16B units) ----
    const float* wsrc = weight + (size_t)ch * (OUT_F * IN_F);
    #pragma unroll
    for (int i = 0; i < 8; ++i) {
        const int fidx = i * 2048 + t * 8;
        const int row  = fidx >> 7;
        const int u    = (fidx & 127) >> 3;
        const float4 f0 = *reinterpret_cast<const float4*>(wsrc + fidx);
        const float4 f1 = *reinterpret_cast<const float4*>(wsrc + fidx + 4);
        const int up = u ^ (row & 7);
        *reinterpret_cast<bf16x8*>(&ldsW[row * IN_F + up * 8]) = cvt_bf16x8(f0, f1);
    }

    // ---- stage bias into LDS once ----
    if (t < 32) {
        const float4 b4 = *reinterpret_cast<const float4*>(bias + (size_t)ch * OUT_F + t * 4);
        *reinterpret_cast<float4*>(&ldsB[t * 4]) = b4;
    }

    __syncthreads();

    // per-lane output base: lane stores float4 at (batch row m = .. + lr, col o = nt*16 + lg*4)
    float* obase = out + (size_t)g * BM * C_SEL * OUT_F
                 + ((size_t)(w * 16 + lr) * C_SEL + (size_t)c) * OUT_F + lg * 4;

    // ---- job loop, manually 2x-unrolled so raA/raB indexing stays static ----
    #pragma unroll
    for (int jj = 0; jj < NJOBS; jj += 2) {
        // ===== even job jj (consumes raA) =====
        {
            // 1) convert landing buffer -> bf16 fragments (raA dies here)
            bf16x8 af[4];
            #pragma unroll
            for (int ks = 0; ks < 4; ++ks) af[ks] = cvt_bf16x8(raA[2 * ks], raA[2 * ks + 1]);

            // 2) immediately issue job jj+2's loads (max lead time before use)
            if (jj + 2 < NJOBS) {
                const float* p = abase + (size_t)(jj + 2) * JSTRIDE;
                #pragma unroll
                for (int ks = 0; ks < 4; ++ks) {
                    raA[2 * ks]     = *reinterpret_cast<const float4*>(p + ks * 32);
                    raA[2 * ks + 1] = *reinterpret_cast<const float4*>(p + ks * 32 + 4);
                }
            }

            // 3) MFMA: D[o][m] = W * In^T  (W = A-operand, In = B-operand)
            f32x4 acc[8];
            #pragma unroll
            for (int nt = 0; nt < 8; ++nt) { f32x4 z = {0.f,0.f,0.f,0.f}; acc[nt] = z; }

            #pragma unroll
            for (int ks = 0; ks < 4; ++ks) {
                #pragma unroll
                for (int nt = 0; nt < 8; ++nt) {
                    const int row = nt * 16 + lr;                 // out feature (W row)
                    const int u   = (ks * 4 + lg) ^ (lr & 7);     // swizzled 16B unit
                    const bf16x8 w8 = *reinterpret_cast<const bf16x8*>(&ldsW[row * IN_F + u * 8]);
                    acc[nt] = __builtin_amdgcn_mfma_f32_16x16x32_bf16(w8, af[ks], acc[nt], 0, 0, 0);
                }
            }

            // 4) tail bias (broadcast ds_read, off critical path) + coalesced store
            float* o = obase + (size_t)jj * JSTRIDE;
            #pragma unroll
            for (int nt = 0; nt < 8; ++nt) {
                const f32x4 b4 = *reinterpret_cast<const f32x4*>(&ldsB[nt * 16 + lg * 4]);
                const f32x4 r  = acc[nt] + b4;
                *reinterpret_cast<float4*>(o + nt * 16) = *reinterpret_cast<const float4*>(&r);
            }
        }
        // ===== odd job jj+1 (consumes raB) =====
        {
            bf16x8 af[4];
            #pragma unroll
            for (int ks = 0; ks < 4; ++ks) af[ks] = cvt_bf16x8(raB[2 * ks], raB[2 * ks + 1]);

            if (jj + 3 < NJOBS) {
                const float* p = abase + (size_t)(jj + 3) * JSTRIDE;
                #pragma unroll
                for (int ks = 0; ks < 4; ++ks) {
                    raB[2 * ks]     = *reinterpret_cast<const float4*>(p + ks * 32);
                    raB[2 * ks + 1] = *reinterpret_cast<const float4*>(p + ks * 32 + 4);
                }
            }

            f32x4 acc[8];
            #pragma unroll
            for (int nt = 0; nt < 8; ++nt) { f32x4 z = {0.f,0.f,0.f,0.f}; acc[nt] = z; }

            #pragma unroll
            for (int ks = 0; ks < 4; ++ks) {
                #pragma unroll
                for (int nt = 0; nt < 8; ++nt) {
                    const int row = nt * 16 + lr;
                    const int u   = (ks * 4 + lg) ^ (lr & 7);
                    const bf16x8 w8 = *reinterpret_cast<const bf16x8*>(&ldsW[row * IN_F + u * 8]);
                    acc[nt] = __builtin_amdgcn_mfma_f32_16x16x32_bf16(w8, af[ks], acc[nt], 0, 0, 0);
                }
            }

            float* o = obase + (size_t)(jj + 1) * JSTRIDE;
            #pragma unroll
            for (int nt = 0; nt < 8; ++nt) {
                const f32x4 b4 = *reinterpret_cast<const f32x4*>(&ldsB[nt * 16 + lg * 4]);
                const f32x4 r  = acc[nt] + b4;
                *reinterpret_cast<float4*>(o + nt * 16) = *reinterpret_cast<const float4*>(&r);
            }
        }
    }
}

extern "C" void kernel_launch(void* const* d_in, const int* in_sizes, int n_in,
                              void* d_out, int out_size, void* d_ws, size_t ws_size,
                              hipStream_t stream) {
    const float* inp      = (const float*)d_in[0];
    const float* weight   = (const float*)d_in[1];
    const float* bias     = (const float*)d_in[2];
    const int*   channels = (const int*)d_in[3];
    float*       out      = (float*)d_out;

    dim3 grid(C_SEL * NGRP);   // 1024 blocks, channel-fastest
    dim3 block(256);
    pl_mfma_kernel<<<grid, block, 0, stream>>>(inp, weight, bias, channels, out);
}

// Round 8
// 113.751 us; speedup vs baseline: 2.1332x; 1.1715x over previous
//
#include <hip/hip_runtime.h>
#include <hip/hip_bf16.h>

// Problem constants (from reference)
#define BATCH   16384
#define C_SEL   32
#define C_TOTAL 64
#define IN_F    128
#define OUT_F   128

#define BM      64    // batch rows per job
#define NGRP    32    // mtile groups (blocks per channel)
#define NJOBS   8     // jobs per block:  NGRP*NJOBS*BM == BATCH

typedef __bf16 bf16x8 __attribute__((ext_vector_type(8)));
typedef float  f32x4  __attribute__((ext_vector_type(4)));

__device__ __forceinline__ bf16x8 cvt_bf16x8(const float4 f0, const float4 f1) {
    bf16x8 a;
    a[0] = (__bf16)f0.x; a[1] = (__bf16)f0.y; a[2] = (__bf16)f0.z; a[3] = (__bf16)f0.w;
    a[4] = (__bf16)f1.x; a[5] = (__bf16)f1.y; a[6] = (__bf16)f1.z; a[7] = (__bf16)f1.w;
    return a;
}

__global__ __launch_bounds__(256, 4) void pl_mfma_kernel(
    const float* __restrict__ inp,       // (BATCH, C_SEL, IN_F)
    const float* __restrict__ weight,    // (C_TOTAL, OUT_F, IN_F)
    const float* __restrict__ bias,      // (C_TOTAL, OUT_F)
    const int*   __restrict__ channels,  // (C_SEL,)
    float*       __restrict__ out)       // (BATCH, C_SEL, OUT_F)
{
    // W[ch] as bf16 [128][128] = 32 KB; bank-conflict-free via 16B-unit XOR swizzle.
    __shared__ __bf16 ldsW[OUT_F * IN_F];

    const int bid = blockIdx.x;          // 1024 blocks
    const int c   = bid & 31;            // channel fastest
    const int g   = bid >> 5;            // mtile group 0..31
    const int ch  = channels[c];

    const int t  = threadIdx.x;
    const int w  = t >> 6;               // wave 0..3 -> rows [w*16, w*16+16) of each job
    const int l  = t & 63;
    const int lr = l & 15;               // fragment row (A) / col (B)
    const int lg = l >> 4;               // k-group 0..3
    const int rot = 2 * w;               // per-wave job rotation (de-lockstep)

    // per-lane A base (floats): job j adds j*JSTRIDE
    const size_t JSTRIDE = (size_t)NGRP * BM * C_SEL * IN_F;   // 8,388,608 floats
    const float* abase = inp + (size_t)g * BM * C_SEL * IN_F
                       + ((size_t)(w * 16 + lr) * C_SEL + (size_t)c) * IN_F + lg * 8;

    // ---- prologue: issue slot-0 and slot-1 A-loads (jobs rot, rot+1) ----
    float4 raA[8], raB[8];
    {
        const float* p0 = abase + (size_t)((0 + rot) & 7) * JSTRIDE;
        #pragma unroll
        for (int ks = 0; ks < 4; ++ks) {
            raA[2 * ks]     = *reinterpret_cast<const float4*>(p0 + ks * 32);
            raA[2 * ks + 1] = *reinterpret_cast<const float4*>(p0 + ks * 32 + 4);
        }
        const float* p1 = abase + (size_t)((1 + rot) & 7) * JSTRIDE;
        #pragma unroll
        for (int ks = 0; ks < 4; ++ks) {
            raB[2 * ks]     = *reinterpret_cast<const float4*>(p1 + ks * 32);
            raB[2 * ks + 1] = *reinterpret_cast<const float4*>(p1 + ks * 32 + 4);
        }
    }

    // ---- bias into 8 registers (lane's column is lr, fixed) ----
    float bv[8];
    const float* brow = bias + (size_t)ch * OUT_F;
    #pragma unroll
    for (int nt = 0; nt < 8; ++nt) bv[nt] = brow[nt * 16 + lr];

    // ---- stage W[ch] fp32 -> bf16 into LDS once (swizzled 16B units) ----
    const float* wsrc = weight + (size_t)ch * (OUT_F * IN_F);
    #pragma unroll
    for (int i = 0; i < 8; ++i) {
        const int fidx = i * 2048 + t * 8;
        const int row  = fidx >> 7;
        const int u    = (fidx & 127) >> 3;
        const float4 f0 = *reinterpret_cast<const float4*>(wsrc + fidx);
        const float4 f1 = *reinterpret_cast<const float4*>(wsrc + fidx + 4);
        const int up = u ^ (row & 7);
        *reinterpret_cast<bf16x8*>(&ldsW[row * IN_F + up * 8]) = cvt_bf16x8(f0, f1);
    }

    __syncthreads();

    // per-lane output base (floats): job j adds j*JSTRIDE, row j2 adds j2*C_SEL*OUT_F
    float* obase = out + (size_t)g * BM * C_SEL * OUT_F
                 + ((size_t)(w * 16 + lg * 4) * C_SEL + (size_t)c) * OUT_F + lr;

    // ---- job loop over slots, 2x-unrolled; wave's job = (slot + rot) & 7 ----
    #pragma unroll
    for (int jj = 0; jj < NJOBS; jj += 2) {
        // ===== even slot jj (consumes raA) =====
        {
            const size_t jobOff = (size_t)((jj + rot) & 7) * JSTRIDE;

            bf16x8 af[4];
            #pragma unroll
            for (int ks = 0; ks < 4; ++ks) af[ks] = cvt_bf16x8(raA[2 * ks], raA[2 * ks + 1]);

            f32x4 acc[8];
            #pragma unroll
            for (int nt = 0; nt < 8; ++nt) { f32x4 z = {0.f,0.f,0.f,0.f}; acc[nt] = z; }

            #pragma unroll
            for (int ks = 0; ks < 4; ++ks) {
                #pragma unroll
                for (int nt = 0; nt < 8; ++nt) {
                    const int row = nt * 16 + lr;
                    const int u   = (ks * 4 + lg) ^ (lr & 7);
                    const bf16x8 b = *reinterpret_cast<const bf16x8*>(&ldsW[row * IN_F + u * 8]);
                    acc[nt] = __builtin_amdgcn_mfma_f32_16x16x32_bf16(af[ks], b, acc[nt], 0, 0, 0);
                }
            }

            // prefetch slot jj+2 into raA (raA fully consumed above)
            if (jj + 2 < NJOBS) {
                const float* p = abase + (size_t)((jj + 2 + rot) & 7) * JSTRIDE;
                #pragma unroll
                for (int ks = 0; ks < 4; ++ks) {
                    raA[2 * ks]     = *reinterpret_cast<const float4*>(p + ks * 32);
                    raA[2 * ks + 1] = *reinterpret_cast<const float4*>(p + ks * 32 + 4);
                }
            }

            float* o = obase + jobOff;
            #pragma unroll
            for (int j2 = 0; j2 < 4; ++j2) {
                #pragma unroll
                for (int nt = 0; nt < 8; ++nt) {
                    o[(size_t)j2 * (C_SEL * OUT_F) + nt * 16] = acc[nt][j2] + bv[nt];
                }
            }
        }
        // ===== odd slot jj+1 (consumes raB) =====
        {
            const size_t jobOff = (size_t)((jj + 1 + rot) & 7) * JSTRIDE;

            bf16x8 af[4];
            #pragma unroll
            for (int ks = 0; ks < 4; ++ks) af[ks] = cvt_bf16x8(raB[2 * ks], raB[2 * ks + 1]);

            f32x4 acc[8];
            #pragma unroll
            for (int nt = 0; nt < 8; ++nt) { f32x4 z = {0.f,0.f,0.f,0.f}; acc[nt] = z; }

            #pragma unroll
            for (int ks = 0; ks < 4; ++ks) {
                #pragma unroll
                for (int nt = 0; nt < 8; ++nt) {
                    const int row = nt * 16 + lr;
                    const int u   = (ks * 4 + lg) ^ (lr & 7);
                    const bf16x8 b = *reinterpret_cast<const bf16x8*>(&ldsW[row * IN_F + u * 8]);
                    acc[nt] = __builtin_amdgcn_mfma_f32_16x16x32_bf16(af[ks], b, acc[nt], 0, 0, 0);
                }
            }

            if (jj + 3 < NJOBS) {
                const float* p = abase + (size_t)((jj + 3 + rot) & 7) * JSTRIDE;
                #pragma unroll
                for (int ks = 0; ks < 4; ++ks) {
                    raB[2 * ks]     = *reinterpret_cast<const float4*>(p + ks * 32);
                    raB[2 * ks + 1] = *reinterpret_cast<const float4*>(p + ks * 32 + 4);
                }
            }

            float* o = obase + jobOff;
            #pragma unroll
            for (int j2 = 0; j2 < 4; ++j2) {
                #pragma unroll
                for (int nt = 0; nt < 8; ++nt) {
                    o[(size_t)j2 * (C_SEL * OUT_F) + nt * 16] = acc[nt][j2] + bv[nt];
                }
            }
        }
    }
}

extern "C" void kernel_launch(void* const* d_in, const int* in_sizes, int n_in,
                              void* d_out, int out_size, void* d_ws, size_t ws_size,
                              hipStream_t stream) {
    const float* inp      = (const float*)d_in[0];
    const float* weight   = (const float*)d_in[1];
    const float* bias     = (const float*)d_in[2];
    const int*   channels = (const int*)d_in[3];
    float*       out      = (float*)d_out;

    dim3 grid(C_SEL * NGRP);   // 1024 blocks, channel-fastest
    dim3 block(256);
    pl_mfma_kernel<<<grid, block, 0, stream>>>(inp, weight, bias, channels, out);
}